// Round 20
// baseline (65.108 us; speedup 1.0000x reference)
//
#include <hip/hip_runtime.h>
#include <hip/hip_bf16.h>

// Problem constants: B=2,C=32,N=4,V=32,W=32,E=256,H=8,D=32,K_H=K_W=7
// L=1024, Bn=8, M=8192.  Internal row ordering: m = bn*1024 + l  (bn-major)
// Residual stream epi_b is bf16 (storage only; all arithmetic fp32).

typedef __attribute__((ext_vector_type(8))) short short8v;   // 8 bf16 (4 VGPR)
typedef __attribute__((ext_vector_type(4))) float f32x4;

__device__ __forceinline__ unsigned short f2bf(float x) {
    union { float f; unsigned u; } c; c.f = x;
    unsigned r = c.u + 0x7FFFu + ((c.u >> 16) & 1u);
    return (unsigned short)(r >> 16);
}
__device__ __forceinline__ float bf2f(short b) {
    union { unsigned u; float f; } c;
    c.u = ((unsigned)(unsigned short)b) << 16;
    return c.f;
}

// ---------------------------------------------------------------------------
// K1: 256 blocks x 512 threads.  32-row gather + input proj (MFMA) + dual LN.
// (unchanged, passing)
// ---------------------------------------------------------------------------
__global__ __launch_bounds__(512) void embed_conv_kernel(
    const float* __restrict__ x_lf, const float* __restrict__ x_hf,
    const float* __restrict__ w_in, const float* __restrict__ w_qk,
    const float* __restrict__ ln_g, const float* __restrict__ ln_b,
    unsigned short* __restrict__ epi_b, unsigned short* __restrict__ kv_b,
    unsigned short* __restrict__ q_b, unsigned short* __restrict__ k_b,
    const float* __restrict__ wqkv, const float* __restrict__ wop,
    const float* __restrict__ wff1, const float* __restrict__ wff2,
    unsigned short* __restrict__ o1, unsigned short* __restrict__ o2,
    unsigned short* __restrict__ o3, unsigned short* __restrict__ o4)
{
    __shared__ float xs[2][32][36];
    __shared__ float part[2][2][2][4][4][2];  // [p][rg][chh][g][r][{s,q}]

    int tid = threadIdx.x;
    int m0 = blockIdx.x * 32;
    int bn = m0 >> 10, l0 = m0 & 1023;
    int bb = bn >> 2, nn = bn & 3;

    {
        int t = tid >> 8, rem = tid & 255;
        int c = rem >> 3, i0 = (rem & 7) * 4;
        size_t base = (size_t)bb * 131072 + (size_t)c * 4096 + nn * 1024 + l0 + i0;
        const float* src = t ? x_hf : x_lf;
        *(float4*)&xs[t][c][i0] = *(const float4*)(src + base);
    }
    __syncthreads();

    int lane = tid & 63, wv = tid >> 6;
    int rA = lane & 15, k8r = lane >> 4, g = k8r, k0 = k8r * 8;
    int p = wv >> 2, rg = (wv >> 1) & 1, chh = wv & 1;
    const float* W = p ? w_qk : w_in;

    short8v afrag;
#pragma unroll
    for (int j = 0; j < 8; ++j)
        afrag[j] = (short)f2bf(xs[p][k0 + j][rg * 16 + rA]);

    f32x4 acc[8];
#pragma unroll
    for (int ct = 0; ct < 8; ++ct)
#pragma unroll
        for (int r = 0; r < 4; ++r) acc[ct][r] = 0.f;

#pragma unroll
    for (int ct = 0; ct < 8; ++ct) {
        const float* wp = W + ((chh * 8 + ct) * 16 + rA) * 32 + k0;
        float4 w0 = *(const float4*)wp;
        float4 w1 = *(const float4*)(wp + 4);
        short8v bfrag;
        bfrag[0] = (short)f2bf(w0.x); bfrag[1] = (short)f2bf(w0.y);
        bfrag[2] = (short)f2bf(w0.z); bfrag[3] = (short)f2bf(w0.w);
        bfrag[4] = (short)f2bf(w1.x); bfrag[5] = (short)f2bf(w1.y);
        bfrag[6] = (short)f2bf(w1.z); bfrag[7] = (short)f2bf(w1.w);
        acc[ct] = __builtin_amdgcn_mfma_f32_16x16x32_bf16(afrag, bfrag, acc[ct], 0, 0, 0);
    }

    float s[4] = {0.f, 0.f, 0.f, 0.f}, q[4] = {0.f, 0.f, 0.f, 0.f};
#pragma unroll
    for (int ct = 0; ct < 8; ++ct)
#pragma unroll
        for (int r = 0; r < 4; ++r) {
            float v = acc[ct][r];
            s[r] += v; q[r] += v * v;
        }
#pragma unroll
    for (int off = 8; off; off >>= 1)
#pragma unroll
        for (int r = 0; r < 4; ++r) {
            s[r] += __shfl_xor(s[r], off);
            q[r] += __shfl_xor(q[r], off);
        }
    if (rA == 0) {
#pragma unroll
        for (int r = 0; r < 4; ++r) {
            part[p][rg][chh][g][r][0] = s[r];
            part[p][rg][chh][g][r][1] = q[r];
        }
    }
    __syncthreads();
    float mu[4], rs[4];
#pragma unroll
    for (int r = 0; r < 4; ++r) {
        float S = part[p][rg][0][g][r][0] + part[p][rg][1][g][r][0];
        float Q = part[p][rg][0][g][r][1] + part[p][rg][1][g][r][1];
        mu[r] = S * (1.f / 256.f);
        rs[r] = rsqrtf(Q * (1.f / 256.f) - mu[r] * mu[r] + 1e-5f);
    }

#pragma unroll
    for (int ct = 0; ct < 8; ++ct) {
        int col = (chh * 8 + ct) * 16 + rA;
        float gg = ln_g[col], bv = ln_b[col];
#pragma unroll
        for (int r = 0; r < 4; ++r) {
            int row = m0 + rg * 16 + g * 4 + r;
            float v = acc[ct][r];
            float lnv = (v - mu[r]) * rs[r] * gg + bv;
            size_t o = (size_t)row * 256 + col;
            if (p == 0) {
                epi_b[o] = f2bf(v);
                q_b[o] = f2bf(lnv);
            } else {
                kv_b[o] = f2bf(v);
                k_b[o] = f2bf(lnv);
            }
        }
    }

    // ---- weight conversion tail: 131072 float4s = 1 per thread ----
    {
        int i4 = blockIdx.x * 512 + tid;
        const float* src; unsigned short* dst; int off;
        if (i4 < 49152)      { src = wqkv; dst = o1; off = i4 * 4; }
        else if (i4 < 65536) { src = wop;  dst = o2; off = (i4 - 49152) * 4; }
        else if (i4 < 98304) { src = wff1; dst = o3; off = (i4 - 65536) * 4; }
        else                 { src = wff2; dst = o4; off = (i4 - 98304) * 4; }
        float4 v = *(const float4*)(src + off);
        ushort4 u;
        u.x = f2bf(v.x); u.y = f2bf(v.y); u.z = f2bf(v.z); u.w = f2bf(v.w);
        *(ushort4*)(dst + off) = u;
    }
}

// ---------------------------------------------------------------------------
// K2: bf16 MFMA GEMM, 64x128 tile, 4 waves, BK=64, global_load_lds staging,
// linear pitch-64 LDS, both-sides XOR chunk swizzle.  (unchanged, passing)
// ---------------------------------------------------------------------------
template <int OUTMAP, bool RELU>
__global__ __launch_bounds__(256) void gemm_mfma64(
    const unsigned short* __restrict__ A0, const unsigned short* __restrict__ A1,
    const unsigned short* __restrict__ A2, const unsigned short* __restrict__ Wb,
    unsigned short* __restrict__ OUT, int K, int N)
{
    int z = blockIdx.z;
    const unsigned short* A = (z == 0) ? A0 : (z == 1) ? A1 : A2;
    const unsigned short* W = Wb + (size_t)z * 65536;

    __shared__ unsigned short As[64 * 64];
    __shared__ unsigned short Ws[128 * 64];

    int tid = threadIdx.x;
    int lane = tid & 63, wid = tid >> 6;
    int wm = wid >> 1, wn = wid & 1;
    int m0 = blockIdx.x * 64, n0 = blockIdx.y * 128;

    f32x4 acc[2][4];
#pragma unroll
    for (int i = 0; i < 2; ++i)
#pragma unroll
        for (int j = 0; j < 4; ++j)
#pragma unroll
            for (int r = 0; r < 4; ++r) acc[i][j][r] = 0.f;

    int rA = lane & 15, k8r = lane >> 4, g = lane >> 4;

    for (int kc = 0; kc < K; kc += 64) {
#pragma unroll
        for (int t = 0; t < 2; ++t) {
            int cb = (t * 4 + wid) * 64;
            int c = cb + lane;
            int row = c >> 3, k8p = (c & 7) ^ (row & 7);
            __builtin_amdgcn_global_load_lds(
                (const unsigned int*)(A + (size_t)(m0 + row) * K + kc + k8p * 8),
                (unsigned int*)&As[cb * 8], 16, 0, 0);
        }
#pragma unroll
        for (int t = 0; t < 4; ++t) {
            int cb = (t * 4 + wid) * 64;
            int c = cb + lane;
            int row = c >> 3, k8p = (c & 7) ^ (row & 7);
            __builtin_amdgcn_global_load_lds(
                (const unsigned int*)(W + (size_t)(n0 + row) * K + kc + k8p * 8),
                (unsigned int*)&Ws[cb * 8], 16, 0, 0);
        }
        __syncthreads();

        short8v a[2][2], b[2][4];
#pragma unroll
        for (int ks = 0; ks < 2; ++ks) {
#pragma unroll
            for (int mi = 0; mi < 2; ++mi) {
                int row = wm * 32 + mi * 16 + rA;
                int cx = (ks * 4 + k8r) ^ (row & 7);
                a[ks][mi] = *(const short8v*)&As[row * 64 + cx * 8];
            }
#pragma unroll
            for (int ni = 0; ni < 4; ++ni) {
                int row = wn * 64 + ni * 16 + rA;
                int cx = (ks * 4 + k8r) ^ (row & 7);
                b[ks][ni] = *(const short8v*)&Ws[row * 64 + cx * 8];
            }
        }
#pragma unroll
        for (int ks = 0; ks < 2; ++ks)
#pragma unroll
            for (int mi = 0; mi < 2; ++mi)
#pragma unroll
                for (int ni = 0; ni < 4; ++ni)
                    acc[mi][ni] = __builtin_amdgcn_mfma_f32_16x16x32_bf16(
                        a[ks][mi], b[ks][ni], acc[mi][ni], 0, 0, 0);
        __syncthreads();
    }

#pragma unroll
    for (int mi = 0; mi < 2; ++mi) {
#pragma unroll
        for (int ni = 0; ni < 4; ++ni) {
#pragma unroll
            for (int r = 0; r < 4; ++r) {
                int row = m0 + wm * 32 + mi * 16 + g * 4 + r;
                int col = n0 + wn * 64 + ni * 16 + rA;
                float v = acc[mi][ni][r];
                if (RELU) v = fmaxf(v, 0.f);
                if (OUTMAP == 0) {
                    OUT[(size_t)row * N + col] = f2bf(v);
                } else {
                    int l = row & 1023, bn = row >> 10;
                    int h = col >> 5, d = col & 31;
                    OUT[(size_t)z * 2097152 + ((bn * 8 + h) * 1024 + l) * 32 + d] = f2bf(v);
                }
            }
        }
    }
}

// ---------------------------------------------------------------------------
// K3: local-window attention, MFMA, 2 qv-rows per block (64 q, 8 kv-rows,
// 256 candidate keys).  K staged via global_load_lds into linear pitch-32
// LDS with 4-chunk XOR swizzle (both sides).  V reg-staged transposed.
// Wave-local softmax; Ks/Ps union; deferred normalization.
// ---------------------------------------------------------------------------
__global__ __launch_bounds__(256) void attn_mfma_kernel(
    const unsigned short* __restrict__ Qb, const unsigned short* __restrict__ Kb,
    const unsigned short* __restrict__ Vb, unsigned short* __restrict__ ctx)
{
    int bh = blockIdx.x >> 4;       // bn*8 + h
    int qv0 = (blockIdx.x & 15) * 2;
    int tid = threadIdx.x, lane = tid & 63, mt = tid >> 6;
    int rA = lane & 15, k8r = lane >> 4, g = lane >> 4;

    __shared__ unsigned short KPs[64 * 264];   // Ks: [n<256][32] lin | Ps: [q<64][264]
    __shared__ unsigned short Vt[32 * 264];    // [d][n], pitch 264

    unsigned short* Ks = KPs;
    unsigned short* Ps = KPs;

    short8v qfrag;
    {
        int qq = mt * 16 + rA;
        int l = (qv0 + (qq >> 5)) * 32 + (qq & 31);
        qfrag = *(const short8v*)(Qb + ((size_t)bh * 1024 + l) * 32 + k8r * 8);
    }

    // K staging: 256 rows x 4 chunks(16B) = 1024 chunks -> 4 gload_lds/wave.
    // Per-lane global source (clamped kv row), linear LDS dest, chunk XOR.
#pragma unroll
    for (int it = 0; it < 4; ++it) {
        int cb = (it * 4 + mt) * 64;          // wave-uniform chunk base
        int c = cb + lane;
        int n = c >> 2, ck = (c & 3) ^ (n & 3);
        int dv = n >> 5, kw = n & 31;
        int kvc = min(max(qv0 - 3 + dv, 0), 31);
        __builtin_amdgcn_global_load_lds(
            (const unsigned int*)(Kb + ((size_t)bh * 1024 + kvc * 32 + kw) * 32 + ck * 8),
            (unsigned int*)&Ks[cb * 8], 16, 0, 0);
    }
    // V staging (register transpose scatter)
#pragma unroll
    for (int it = 0; it < 4; ++it) {
        int idx = it * 256 + tid;
        int dv = idx >> 7, rem = idx & 127;
        int kw = rem >> 2, c8 = (rem & 3) * 8;
        int kvc = min(max(qv0 - 3 + dv, 0), 31);
        size_t base = ((size_t)bh * 1024 + kvc * 32 + kw) * 32 + c8;
        int n = dv * 32 + kw;
        short8v v8 = *(const short8v*)(Vb + base);
#pragma unroll
        for (int j = 0; j < 8; ++j)
            Vt[(c8 + j) * 264 + n] = (unsigned short)v8[j];
    }
    __syncthreads();

    f32x4 sc[16];
#pragma unroll
    for (int ct = 0; ct < 16; ++ct)
#pragma unroll
        for (int r = 0; r < 4; ++r) sc[ct][r] = 0.f;
#pragma unroll
    for (int ct = 0; ct < 16; ++ct) {
        int row = ct * 16 + rA;
        int cx = k8r ^ (row & 3);
        short8v b = *(const short8v*)&Ks[row * 32 + cx * 8];
        sc[ct] = __builtin_amdgcn_mfma_f32_16x16x32_bf16(qfrag, b, sc[ct], 0, 0, 0);
    }
    __syncthreads();   // all waves done reading Ks before Ps overlay writes

    const float scale = 0.17677669529663687f;
    float mx[4] = {-1e30f, -1e30f, -1e30f, -1e30f};
#pragma unroll
    for (int ct = 0; ct < 16; ++ct) {
        int n = ct * 16 + rA;
        int dv = n >> 5, kw = n & 31;
        int kv = qv0 - 3 + dv;
        bool vok = (kv >= 0) && (kv < 32);
#pragma unroll
        for (int r = 0; r < 4; ++r) {
            int qq = mt * 16 + g * 4 + r;
            int v = qv0 + (qq >> 5), w = qq & 31;
            int djv = kv - v, djw = kw - w;
            bool ok = vok && (djv >= -3) && (djv <= 3) && (djw >= -3) && (djw <= 3);
            float s = ok ? sc[ct][r] * scale : -1e30f;
            sc[ct][r] = s;
            mx[r] = fmaxf(mx[r], s);
        }
    }
#pragma unroll
    for (int off = 8; off; off >>= 1)
#pragma unroll
        for (int r = 0; r < 4; ++r) mx[r] = fmaxf(mx[r], __shfl_xor(mx[r], off));

    float sm[4] = {0.f, 0.f, 0.f, 0.f};
#pragma unroll
    for (int ct = 0; ct < 16; ++ct)
#pragma unroll
        for (int r = 0; r < 4; ++r) {
            float e = __expf(sc[ct][r] - mx[r]);
            sc[ct][r] = e;
            sm[r] += e;
        }
#pragma unroll
    for (int off = 8; off; off >>= 1)
#pragma unroll
        for (int r = 0; r < 4; ++r) sm[r] += __shfl_xor(sm[r], off);
    float inv[4];
#pragma unroll
    for (int r = 0; r < 4; ++r) inv[r] = 1.f / sm[r];

#pragma unroll
    for (int ct = 0; ct < 16; ++ct) {
        int n = ct * 16 + rA;
#pragma unroll
        for (int r = 0; r < 4; ++r) {
            int q = mt * 16 + g * 4 + r;
            Ps[q * 264 + n] = f2bf(sc[ct][r]);
        }
    }
    __syncthreads();

    f32x4 o[2];
#pragma unroll
    for (int dt = 0; dt < 2; ++dt)
#pragma unroll
        for (int r = 0; r < 4; ++r) o[dt][r] = 0.f;
#pragma unroll
    for (int kb = 0; kb < 8; ++kb) {
        short8v pa = *(const short8v*)&Ps[(mt * 16 + rA) * 264 + kb * 32 + k8r * 8];
#pragma unroll
        for (int dt = 0; dt < 2; ++dt) {
            short8v vb = *(const short8v*)&Vt[(dt * 16 + rA) * 264 + kb * 32 + k8r * 8];
            o[dt] = __builtin_amdgcn_mfma_f32_16x16x32_bf16(pa, vb, o[dt], 0, 0, 0);
        }
    }

    {
        int bn = bh >> 3, h = bh & 7;
#pragma unroll
        for (int dt = 0; dt < 2; ++dt) {
            int d = dt * 16 + rA;
#pragma unroll
            for (int r = 0; r < 4; ++r) {
                int qq = mt * 16 + g * 4 + r;
                int l = (qv0 + (qq >> 5)) * 32 + (qq & 31);
                ctx[((size_t)bn * 1024 + l) * 256 + h * 32 + d] = f2bf(o[dt][r] * inv[r]);
            }
        }
    }
}

// ---------------------------------------------------------------------------
// K4: out_proj + residual(bf16) + LN2.  32-row tile, 512 threads / 8 waves,
// BK=64, global_load_lds staging.  (unchanged, passing)
// ---------------------------------------------------------------------------
__global__ __launch_bounds__(512) void outproj_ln_kernel(
    const unsigned short* __restrict__ ctx, const unsigned short* __restrict__ Wop,
    unsigned short* __restrict__ epi_b, const float* __restrict__ g2,
    const float* __restrict__ b2, unsigned short* __restrict__ ffin)
{
    __shared__ unsigned short As[32 * 64];
    __shared__ unsigned short Ws[256 * 64];
    __shared__ float part[2][4][4][4][2];

    int tid = threadIdx.x, lane = tid & 63, wv = tid >> 6;
    int m0 = blockIdx.x * 32;
    int rA = lane & 15, k8r = lane >> 4, g = lane >> 4;
    int rg = wv & 1, ch = wv >> 1;

    f32x4 acc[4];
#pragma unroll
    for (int ct = 0; ct < 4; ++ct)
#pragma unroll
        for (int r = 0; r < 4; ++r) acc[ct][r] = 0.f;

    for (int kc = 0; kc < 256; kc += 64) {
        if (wv < 4) {
            int cb = wv * 64;
            int c = cb + lane;
            int row = c >> 3, k8p = (c & 7) ^ (row & 7);
            __builtin_amdgcn_global_load_lds(
                (const unsigned int*)(ctx + (size_t)(m0 + row) * 256 + kc + k8p * 8),
                (unsigned int*)&As[cb * 8], 16, 0, 0);
        }
#pragma unroll
        for (int t = 0; t < 4; ++t) {
            int cb = (t * 8 + wv) * 64;
            int c = cb + lane;
            int row = c >> 3, k8p = (c & 7) ^ (row & 7);
            __builtin_amdgcn_global_load_lds(
                (const unsigned int*)(Wop + (size_t)row * 256 + kc + k8p * 8),
                (unsigned int*)&Ws[cb * 8], 16, 0, 0);
        }
        __syncthreads();

        short8v a[2];
#pragma unroll
        for (int ks = 0; ks < 2; ++ks) {
            int row = rg * 16 + rA;
            int cx = (ks * 4 + k8r) ^ (row & 7);
            a[ks] = *(const short8v*)&As[row * 64 + cx * 8];
        }
#pragma unroll
        for (int ks = 0; ks < 2; ++ks)
#pragma unroll
            for (int ct = 0; ct < 4; ++ct) {
                int row = ch * 64 + ct * 16 + rA;
                int cx = (ks * 4 + k8r) ^ (row & 7);
                short8v b = *(const short8v*)&Ws[row * 64 + cx * 8];
                acc[ct] = __builtin_amdgcn_mfma_f32_16x16x32_bf16(a[ks], b, acc[ct], 0, 0, 0);
            }
        __syncthreads();
    }

    float s[4] = {0.f, 0.f, 0.f, 0.f}, q[4] = {0.f, 0.f, 0.f, 0.f};
#pragma unroll
    for (int ct = 0; ct < 4; ++ct) {
        int col = ch * 64 + ct * 16 + rA;
#pragma unroll
        for (int r = 0; r < 4; ++r) {
            int row = m0 + rg * 16 + g * 4 + r;
            float v = acc[ct][r] + bf2f(epi_b[(size_t)row * 256 + col]);
            acc[ct][r] = v;
            s[r] += v; q[r] += v * v;
        }
    }
#pragma unroll
    for (int off = 8; off; off >>= 1)
#pragma unroll
        for (int r = 0; r < 4; ++r) {
            s[r] += __shfl_xor(s[r], off);
            q[r] += __shfl_xor(q[r], off);
        }
    if (rA == 0) {
#pragma unroll
        for (int r = 0; r < 4; ++r) {
            part[rg][ch][g][r][0] = s[r];
            part[rg][ch][g][r][1] = q[r];
        }
    }
    __syncthreads();
    float mu[4], rs[4];
#pragma unroll
    for (int r = 0; r < 4; ++r) {
        float S = part[rg][0][g][r][0] + part[rg][1][g][r][0]
                + part[rg][2][g][r][0] + part[rg][3][g][r][0];
        float Q = part[rg][0][g][r][1] + part[rg][1][g][r][1]
                + part[rg][2][g][r][1] + part[rg][3][g][r][1];
        mu[r] = S * (1.f / 256.f);
        rs[r] = rsqrtf(Q * (1.f / 256.f) - mu[r] * mu[r] + 1e-5f);
    }
#pragma unroll
    for (int ct = 0; ct < 4; ++ct) {
        int col = ch * 64 + ct * 16 + rA;
        float gg = g2[col], bv = b2[col];
#pragma unroll
        for (int r = 0; r < 4; ++r) {
            int row = m0 + rg * 16 + g * 4 + r;
            size_t o = (size_t)row * 256 + col;
            epi_b[o] = f2bf(acc[ct][r]);
            ffin[o] = f2bf((acc[ct][r] - mu[r]) * rs[r] * gg + bv);
        }
    }
}

// ---------------------------------------------------------------------------
// K6: FF2 + residual(bf16) + final E->32 projection + transposed store.
// 32-row tile, 512 threads / 8 waves, BK=64, global_load_lds staging.
// (unchanged, passing)
// ---------------------------------------------------------------------------
__global__ __launch_bounds__(512) void ff2_final_kernel(
    const unsigned short* __restrict__ ffh, const unsigned short* __restrict__ W2,
    const unsigned short* __restrict__ epi_b, const float* __restrict__ w_out,
    float* __restrict__ out)
{
    __shared__ unsigned short As[32 * 64];
    __shared__ unsigned short Ws[256 * 64];
    __shared__ unsigned short Ts[32 * 264];

    int tid = threadIdx.x, lane = tid & 63, wv = tid >> 6;
    int m0 = blockIdx.x * 32;
    int rA = lane & 15, k8r = lane >> 4, g = lane >> 4;
    int rg = wv & 1, ch = wv >> 1;

    f32x4 acc[4];
#pragma unroll
    for (int ct = 0; ct < 4; ++ct)
#pragma unroll
        for (int r = 0; r < 4; ++r) acc[ct][r] = 0.f;

    for (int kc = 0; kc < 512; kc += 64) {
        if (wv < 4) {
            int cb = wv * 64;
            int c = cb + lane;
            int row = c >> 3, k8p = (c & 7) ^ (row & 7);
            __builtin_amdgcn_global_load_lds(
                (const unsigned int*)(ffh + (size_t)(m0 + row) * 512 + kc + k8p * 8),
                (unsigned int*)&As[cb * 8], 16, 0, 0);
        }
#pragma unroll
        for (int t = 0; t < 4; ++t) {
            int cb = (t * 8 + wv) * 64;
            int c = cb + lane;
            int row = c >> 3, k8p = (c & 7) ^ (row & 7);
            __builtin_amdgcn_global_load_lds(
                (const unsigned int*)(W2 + (size_t)row * 512 + kc + k8p * 8),
                (unsigned int*)&Ws[cb * 8], 16, 0, 0);
        }
        __syncthreads();

        short8v a[2];
#pragma unroll
        for (int ks = 0; ks < 2; ++ks) {
            int row = rg * 16 + rA;
            int cx = (ks * 4 + k8r) ^ (row & 7);
            a[ks] = *(const short8v*)&As[row * 64 + cx * 8];
        }
#pragma unroll
        for (int ks = 0; ks < 2; ++ks)
#pragma unroll
            for (int ct = 0; ct < 4; ++ct) {
                int row = ch * 64 + ct * 16 + rA;
                int cx = (ks * 4 + k8r) ^ (row & 7);
                short8v b = *(const short8v*)&Ws[row * 64 + cx * 8];
                acc[ct] = __builtin_amdgcn_mfma_f32_16x16x32_bf16(a[ks], b, acc[ct], 0, 0, 0);
            }
        __syncthreads();
    }

#pragma unroll
    for (int ct = 0; ct < 4; ++ct) {
        int col = ch * 64 + ct * 16 + rA;
#pragma unroll
        for (int r = 0; r < 4; ++r) {
            int lrow = rg * 16 + g * 4 + r;
            float v = acc[ct][r] + bf2f(epi_b[(size_t)(m0 + lrow) * 256 + col]);
            Ts[lrow * 264 + col] = f2bf(v);
        }
    }
    __syncthreads();

    int bn = m0 >> 10, l0 = m0 & 1023;
    int bb = bn >> 2, nn = bn & 3;

    if (wv < 4) {
        int rw = wv & 1, cw = wv >> 1;
        f32x4 a2;
#pragma unroll
        for (int r = 0; r < 4; ++r) a2[r] = 0.f;
#pragma unroll
        for (int ks = 0; ks < 8; ++ks) {
            short8v af = *(const short8v*)&Ts[(rw * 16 + rA) * 264 + ks * 32 + k8r * 8];
            const float* wp = w_out + (cw * 16 + rA) * 256 + ks * 32 + k8r * 8;
            float4 w0 = *(const float4*)wp;
            float4 w1 = *(const float4*)(wp + 4);
            short8v bf;
            bf[0] = (short)f2bf(w0.x); bf[1] = (short)f2bf(w0.y);
            bf[2] = (short)f2bf(w0.z); bf[3] = (short)f2bf(w0.w);
            bf[4] = (short)f2bf(w1.x); bf[5] = (short)f2bf(w1.y);
            bf[6] = (short)f2bf(w1.z); bf[7] = (short)f2bf(w1.w);
            a2 = __builtin_amdgcn_mfma_f32_16x16x32_bf16(af, bf, a2, 0, 0, 0);
        }
        int c = cw * 16 + rA;
        int l = l0 + rw * 16 + g * 4;
        float4 st; st.x = a2[0]; st.y = a2[1]; st.z = a2[2]; st.w = a2[3];
        *(float4*)(out + ((size_t)(bb * 32 + c) * 4 + nn) * 1024 + l) = st;
    }
}

// ---------------------------------------------------------------------------
extern "C" void kernel_launch(void* const* d_in, const int* in_sizes, int n_in,
                              void* d_out, int out_size, void* d_ws, size_t ws_size,
                              hipStream_t stream) {
    const float* x_lf       = (const float*)d_in[0];
    const float* x_hf       = (const float*)d_in[1];
    const float* w_in       = (const float*)d_in[2];
    const float* w_qk       = (const float*)d_in[3];
    const float* ln_g       = (const float*)d_in[4];
    const float* ln_b       = (const float*)d_in[5];
    const float* in_proj_w  = (const float*)d_in[6];
    const float* out_proj_w = (const float*)d_in[7];
    const float* ln2_g      = (const float*)d_in[8];
    const float* ln2_b      = (const float*)d_in[9];
    const float* ff_w1      = (const float*)d_in[10];
    const float* ff_w2      = (const float*)d_in[11];
    const float* w_out      = (const float*)d_in[12];
    float* out = (float*)d_out;

    char* w = (char*)d_ws;
    unsigned short* epi_b  = (unsigned short*)(w);                // 4 MB bf16
    unsigned short* Qb     = (unsigned short*)(w + (4u  << 20));  // 4 MB bf16
    unsigned short* Kb     = (unsigned short*)(w + (8u  << 20));
    unsigned short* Vb     = (unsigned short*)(w + (12u << 20));
    unsigned short* q_b    = (unsigned short*)(w + (16u << 20));
    unsigned short* k_b    = (unsigned short*)(w + (20u << 20));
    unsigned short* kv_b   = (unsigned short*)(w + (24u << 20));
    unsigned short* ctx_b  = (unsigned short*)(w + (28u << 20));
    unsigned short* ffin_b = (unsigned short*)(w + (32u << 20));
    unsigned short* ffh_b  = (unsigned short*)(w + (36u << 20));  // 8 MB
    unsigned short* wqkv_b = (unsigned short*)(w + (44u << 20));
    unsigned short* wop_b  = (unsigned short*)(w + (45u << 20));
    unsigned short* wff1_b = (unsigned short*)(w + (46u << 20));
    unsigned short* wff2_b = (unsigned short*)(w + (47u << 20));

    // 1. gather + input proj + dual LN + weight conversion  [256 blk x 512]
    embed_conv_kernel<<<256, 512, 0, stream>>>(
        x_lf, x_hf, w_in, w_qk, ln_g, ln_b, epi_b, kv_b, q_b, k_b,
        in_proj_w, out_proj_w, ff_w1, ff_w2, wqkv_b, wop_b, wff1_b, wff2_b);
    // 2. QKV projection -> bf16 (bn,h,l,d)   [768 blocks, gload_lds]
    gemm_mfma64<1, false><<<dim3(128, 2, 3), 256, 0, stream>>>(
        q_b, k_b, kv_b, wqkv_b, Qb, 256, 256);
    // 3. local-window attention (MFMA, K via gload_lds) -> ctx bf16
    attn_mfma_kernel<<<1024, 256, 0, stream>>>(Qb, Kb, Vb, ctx_b);
    // 4. out_proj + residual(bf16) + LN2  [512 thr, gload_lds]
    outproj_ln_kernel<<<256, 512, 0, stream>>>(ctx_b, wop_b, epi_b,
                                               ln2_g, ln2_b, ffin_b);
    // 5. FF1 + ReLU -> bf16 [8192,512]   [512 blocks, gload_lds]
    gemm_mfma64<0, true><<<dim3(128, 4, 1), 256, 0, stream>>>(
        ffin_b, ffin_b, ffin_b, wff1_b, ffh_b, 256, 512);
    // 6. FF2 + residual(bf16) + final projection + transposed store
    ff2_final_kernel<<<256, 512, 0, stream>>>(ffh_b, wff2_b, epi_b, w_out, out);
}

// Round 21
// 64.143 us; speedup vs baseline: 1.0150x; 1.0150x over previous
//
#include <hip/hip_runtime.h>
#include <hip/hip_bf16.h>

// Problem constants: B=2,C=32,N=4,V=32,W=32,E=256,H=8,D=32,K_H=K_W=7
// L=1024, Bn=8, M=8192.  Internal row ordering: m = bn*1024 + l  (bn-major)
// Residual stream epi_b is bf16 (storage only; all arithmetic fp32).

typedef __attribute__((ext_vector_type(8))) short short8v;   // 8 bf16 (4 VGPR)
typedef __attribute__((ext_vector_type(4))) float f32x4;

__device__ __forceinline__ unsigned short f2bf(float x) {
    union { float f; unsigned u; } c; c.f = x;
    unsigned r = c.u + 0x7FFFu + ((c.u >> 16) & 1u);
    return (unsigned short)(r >> 16);
}
__device__ __forceinline__ float bf2f(short b) {
    union { unsigned u; float f; } c;
    c.u = ((unsigned)(unsigned short)b) << 16;
    return c.f;
}

// ---------------------------------------------------------------------------
// K1: 256 blocks x 512 threads.  32-row gather + input proj (MFMA) + dual LN.
// ---------------------------------------------------------------------------
__global__ __launch_bounds__(512) void embed_conv_kernel(
    const float* __restrict__ x_lf, const float* __restrict__ x_hf,
    const float* __restrict__ w_in, const float* __restrict__ w_qk,
    const float* __restrict__ ln_g, const float* __restrict__ ln_b,
    unsigned short* __restrict__ epi_b, unsigned short* __restrict__ kv_b,
    unsigned short* __restrict__ q_b, unsigned short* __restrict__ k_b,
    const float* __restrict__ wqkv, const float* __restrict__ wop,
    const float* __restrict__ wff1, const float* __restrict__ wff2,
    unsigned short* __restrict__ o1, unsigned short* __restrict__ o2,
    unsigned short* __restrict__ o3, unsigned short* __restrict__ o4)
{
    __shared__ float xs[2][32][36];
    __shared__ float part[2][2][2][4][4][2];  // [p][rg][chh][g][r][{s,q}]

    int tid = threadIdx.x;
    int m0 = blockIdx.x * 32;
    int bn = m0 >> 10, l0 = m0 & 1023;
    int bb = bn >> 2, nn = bn & 3;

    {
        int t = tid >> 8, rem = tid & 255;
        int c = rem >> 3, i0 = (rem & 7) * 4;
        size_t base = (size_t)bb * 131072 + (size_t)c * 4096 + nn * 1024 + l0 + i0;
        const float* src = t ? x_hf : x_lf;
        *(float4*)&xs[t][c][i0] = *(const float4*)(src + base);
    }
    __syncthreads();

    int lane = tid & 63, wv = tid >> 6;
    int rA = lane & 15, k8r = lane >> 4, g = k8r, k0 = k8r * 8;
    int p = wv >> 2, rg = (wv >> 1) & 1, chh = wv & 1;
    const float* W = p ? w_qk : w_in;

    short8v afrag;
#pragma unroll
    for (int j = 0; j < 8; ++j)
        afrag[j] = (short)f2bf(xs[p][k0 + j][rg * 16 + rA]);

    f32x4 acc[8];
#pragma unroll
    for (int ct = 0; ct < 8; ++ct)
#pragma unroll
        for (int r = 0; r < 4; ++r) acc[ct][r] = 0.f;

#pragma unroll
    for (int ct = 0; ct < 8; ++ct) {
        const float* wp = W + ((chh * 8 + ct) * 16 + rA) * 32 + k0;
        float4 w0 = *(const float4*)wp;
        float4 w1 = *(const float4*)(wp + 4);
        short8v bfrag;
        bfrag[0] = (short)f2bf(w0.x); bfrag[1] = (short)f2bf(w0.y);
        bfrag[2] = (short)f2bf(w0.z); bfrag[3] = (short)f2bf(w0.w);
        bfrag[4] = (short)f2bf(w1.x); bfrag[5] = (short)f2bf(w1.y);
        bfrag[6] = (short)f2bf(w1.z); bfrag[7] = (short)f2bf(w1.w);
        acc[ct] = __builtin_amdgcn_mfma_f32_16x16x32_bf16(afrag, bfrag, acc[ct], 0, 0, 0);
    }

    float s[4] = {0.f, 0.f, 0.f, 0.f}, q[4] = {0.f, 0.f, 0.f, 0.f};
#pragma unroll
    for (int ct = 0; ct < 8; ++ct)
#pragma unroll
        for (int r = 0; r < 4; ++r) {
            float v = acc[ct][r];
            s[r] += v; q[r] += v * v;
        }
#pragma unroll
    for (int off = 8; off; off >>= 1)
#pragma unroll
        for (int r = 0; r < 4; ++r) {
            s[r] += __shfl_xor(s[r], off);
            q[r] += __shfl_xor(q[r], off);
        }
    if (rA == 0) {
#pragma unroll
        for (int r = 0; r < 4; ++r) {
            part[p][rg][chh][g][r][0] = s[r];
            part[p][rg][chh][g][r][1] = q[r];
        }
    }
    __syncthreads();
    float mu[4], rs[4];
#pragma unroll
    for (int r = 0; r < 4; ++r) {
        float S = part[p][rg][0][g][r][0] + part[p][rg][1][g][r][0];
        float Q = part[p][rg][0][g][r][1] + part[p][rg][1][g][r][1];
        mu[r] = S * (1.f / 256.f);
        rs[r] = rsqrtf(Q * (1.f / 256.f) - mu[r] * mu[r] + 1e-5f);
    }

#pragma unroll
    for (int ct = 0; ct < 8; ++ct) {
        int col = (chh * 8 + ct) * 16 + rA;
        float gg = ln_g[col], bv = ln_b[col];
#pragma unroll
        for (int r = 0; r < 4; ++r) {
            int row = m0 + rg * 16 + g * 4 + r;
            float v = acc[ct][r];
            float lnv = (v - mu[r]) * rs[r] * gg + bv;
            size_t o = (size_t)row * 256 + col;
            if (p == 0) {
                epi_b[o] = f2bf(v);
                q_b[o] = f2bf(lnv);
            } else {
                kv_b[o] = f2bf(v);
                k_b[o] = f2bf(lnv);
            }
        }
    }

    // ---- weight conversion tail: 131072 float4s = 1 per thread ----
    {
        int i4 = blockIdx.x * 512 + tid;
        const float* src; unsigned short* dst; int off;
        if (i4 < 49152)      { src = wqkv; dst = o1; off = i4 * 4; }
        else if (i4 < 65536) { src = wop;  dst = o2; off = (i4 - 49152) * 4; }
        else if (i4 < 98304) { src = wff1; dst = o3; off = (i4 - 65536) * 4; }
        else                 { src = wff2; dst = o4; off = (i4 - 98304) * 4; }
        float4 v = *(const float4*)(src + off);
        ushort4 u;
        u.x = f2bf(v.x); u.y = f2bf(v.y); u.z = f2bf(v.z); u.w = f2bf(v.w);
        *(ushort4*)(dst + off) = u;
    }
}

// ---------------------------------------------------------------------------
// K2: bf16 MFMA GEMM, 64x128 tile, 4 waves, BK=64, global_load_lds staging,
// linear pitch-64 LDS, both-sides XOR chunk swizzle.
// ---------------------------------------------------------------------------
template <int OUTMAP, bool RELU>
__global__ __launch_bounds__(256) void gemm_mfma64(
    const unsigned short* __restrict__ A0, const unsigned short* __restrict__ A1,
    const unsigned short* __restrict__ A2, const unsigned short* __restrict__ Wb,
    unsigned short* __restrict__ OUT, int K, int N)
{
    int z = blockIdx.z;
    const unsigned short* A = (z == 0) ? A0 : (z == 1) ? A1 : A2;
    const unsigned short* W = Wb + (size_t)z * 65536;

    __shared__ unsigned short As[64 * 64];
    __shared__ unsigned short Ws[128 * 64];

    int tid = threadIdx.x;
    int lane = tid & 63, wid = tid >> 6;
    int wm = wid >> 1, wn = wid & 1;
    int m0 = blockIdx.x * 64, n0 = blockIdx.y * 128;

    f32x4 acc[2][4];
#pragma unroll
    for (int i = 0; i < 2; ++i)
#pragma unroll
        for (int j = 0; j < 4; ++j)
#pragma unroll
            for (int r = 0; r < 4; ++r) acc[i][j][r] = 0.f;

    int rA = lane & 15, k8r = lane >> 4, g = lane >> 4;

    for (int kc = 0; kc < K; kc += 64) {
#pragma unroll
        for (int t = 0; t < 2; ++t) {
            int cb = (t * 4 + wid) * 64;
            int c = cb + lane;
            int row = c >> 3, k8p = (c & 7) ^ (row & 7);
            __builtin_amdgcn_global_load_lds(
                (const unsigned int*)(A + (size_t)(m0 + row) * K + kc + k8p * 8),
                (unsigned int*)&As[cb * 8], 16, 0, 0);
        }
#pragma unroll
        for (int t = 0; t < 4; ++t) {
            int cb = (t * 4 + wid) * 64;
            int c = cb + lane;
            int row = c >> 3, k8p = (c & 7) ^ (row & 7);
            __builtin_amdgcn_global_load_lds(
                (const unsigned int*)(W + (size_t)(n0 + row) * K + kc + k8p * 8),
                (unsigned int*)&Ws[cb * 8], 16, 0, 0);
        }
        __syncthreads();

        short8v a[2][2], b[2][4];
#pragma unroll
        for (int ks = 0; ks < 2; ++ks) {
#pragma unroll
            for (int mi = 0; mi < 2; ++mi) {
                int row = wm * 32 + mi * 16 + rA;
                int cx = (ks * 4 + k8r) ^ (row & 7);
                a[ks][mi] = *(const short8v*)&As[row * 64 + cx * 8];
            }
#pragma unroll
            for (int ni = 0; ni < 4; ++ni) {
                int row = wn * 64 + ni * 16 + rA;
                int cx = (ks * 4 + k8r) ^ (row & 7);
                b[ks][ni] = *(const short8v*)&Ws[row * 64 + cx * 8];
            }
        }
#pragma unroll
        for (int ks = 0; ks < 2; ++ks)
#pragma unroll
            for (int mi = 0; mi < 2; ++mi)
#pragma unroll
                for (int ni = 0; ni < 4; ++ni)
                    acc[mi][ni] = __builtin_amdgcn_mfma_f32_16x16x32_bf16(
                        a[ks][mi], b[ks][ni], acc[mi][ni], 0, 0, 0);
        __syncthreads();
    }

#pragma unroll
    for (int mi = 0; mi < 2; ++mi) {
#pragma unroll
        for (int ni = 0; ni < 4; ++ni) {
#pragma unroll
            for (int r = 0; r < 4; ++r) {
                int row = m0 + wm * 32 + mi * 16 + g * 4 + r;
                int col = n0 + wn * 64 + ni * 16 + rA;
                float v = acc[mi][ni][r];
                if (RELU) v = fmaxf(v, 0.f);
                if (OUTMAP == 0) {
                    OUT[(size_t)row * N + col] = f2bf(v);
                } else {
                    int l = row & 1023, bn = row >> 10;
                    int h = col >> 5, d = col & 31;
                    OUT[(size_t)z * 2097152 + ((bn * 8 + h) * 1024 + l) * 32 + d] = f2bf(v);
                }
            }
        }
    }
}

// ---------------------------------------------------------------------------
// K3: local-window attention, MFMA, 2 qv-rows per block (64 q, 8 kv-rows,
// 256 candidate keys).  Reg-staged K (pitch 40) + V transposed.  Wave-local
// softmax; Ks/Ps union; deferred normalization.  (R18 version, best measured)
// ---------------------------------------------------------------------------
__global__ __launch_bounds__(256) void attn_mfma_kernel(
    const unsigned short* __restrict__ Qb, const unsigned short* __restrict__ Kb,
    const unsigned short* __restrict__ Vb, unsigned short* __restrict__ ctx)
{
    int bh = blockIdx.x >> 4;       // bn*8 + h
    int qv0 = (blockIdx.x & 15) * 2;
    int tid = threadIdx.x, lane = tid & 63, mt = tid >> 6;
    int rA = lane & 15, k8r = lane >> 4, g = lane >> 4;

    __shared__ unsigned short KPs[64 * 264];   // Ks: [n<256][40] | Ps: [q<64][264]
    __shared__ unsigned short Vt[32 * 264];    // [d][n], pitch 264

    unsigned short* Ks = KPs;
    unsigned short* Ps = KPs;

    short8v qfrag;
    {
        int qq = mt * 16 + rA;
        int l = (qv0 + (qq >> 5)) * 32 + (qq & 31);
        qfrag = *(const short8v*)(Qb + ((size_t)bh * 1024 + l) * 32 + k8r * 8);
    }

#pragma unroll
    for (int it = 0; it < 4; ++it) {
        int idx = it * 256 + tid;
        int dv = idx >> 7, rem = idx & 127;
        int kw = rem >> 2, c8 = (rem & 3) * 8;
        int kvc = min(max(qv0 - 3 + dv, 0), 31);
        size_t base = ((size_t)bh * 1024 + kvc * 32 + kw) * 32 + c8;
        int n = dv * 32 + kw;
        *(short8v*)&Ks[n * 40 + c8] = *(const short8v*)(Kb + base);
        short8v v8 = *(const short8v*)(Vb + base);
#pragma unroll
        for (int j = 0; j < 8; ++j)
            Vt[(c8 + j) * 264 + n] = (unsigned short)v8[j];
    }
    __syncthreads();

    f32x4 sc[16];
#pragma unroll
    for (int ct = 0; ct < 16; ++ct)
#pragma unroll
        for (int r = 0; r < 4; ++r) sc[ct][r] = 0.f;
#pragma unroll
    for (int ct = 0; ct < 16; ++ct) {
        short8v b = *(const short8v*)&Ks[(ct * 16 + rA) * 40 + k8r * 8];
        sc[ct] = __builtin_amdgcn_mfma_f32_16x16x32_bf16(qfrag, b, sc[ct], 0, 0, 0);
    }
    __syncthreads();   // all waves done reading Ks before Ps overlay writes

    const float scale = 0.17677669529663687f;
    float mx[4] = {-1e30f, -1e30f, -1e30f, -1e30f};
#pragma unroll
    for (int ct = 0; ct < 16; ++ct) {
        int n = ct * 16 + rA;
        int dv = n >> 5, kw = n & 31;
        int kv = qv0 - 3 + dv;
        bool vok = (kv >= 0) && (kv < 32);
#pragma unroll
        for (int r = 0; r < 4; ++r) {
            int qq = mt * 16 + g * 4 + r;
            int v = qv0 + (qq >> 5), w = qq & 31;
            int djv = kv - v, djw = kw - w;
            bool ok = vok && (djv >= -3) && (djv <= 3) && (djw >= -3) && (djw <= 3);
            float s = ok ? sc[ct][r] * scale : -1e30f;
            sc[ct][r] = s;
            mx[r] = fmaxf(mx[r], s);
        }
    }
#pragma unroll
    for (int off = 8; off; off >>= 1)
#pragma unroll
        for (int r = 0; r < 4; ++r) mx[r] = fmaxf(mx[r], __shfl_xor(mx[r], off));

    float sm[4] = {0.f, 0.f, 0.f, 0.f};
#pragma unroll
    for (int ct = 0; ct < 16; ++ct)
#pragma unroll
        for (int r = 0; r < 4; ++r) {
            float e = __expf(sc[ct][r] - mx[r]);
            sc[ct][r] = e;
            sm[r] += e;
        }
#pragma unroll
    for (int off = 8; off; off >>= 1)
#pragma unroll
        for (int r = 0; r < 4; ++r) sm[r] += __shfl_xor(sm[r], off);
    float inv[4];
#pragma unroll
    for (int r = 0; r < 4; ++r) inv[r] = 1.f / sm[r];

#pragma unroll
    for (int ct = 0; ct < 16; ++ct) {
        int n = ct * 16 + rA;
#pragma unroll
        for (int r = 0; r < 4; ++r) {
            int q = mt * 16 + g * 4 + r;
            Ps[q * 264 + n] = f2bf(sc[ct][r]);
        }
    }
    __syncthreads();

    f32x4 o[2];
#pragma unroll
    for (int dt = 0; dt < 2; ++dt)
#pragma unroll
        for (int r = 0; r < 4; ++r) o[dt][r] = 0.f;
#pragma unroll
    for (int kb = 0; kb < 8; ++kb) {
        short8v pa = *(const short8v*)&Ps[(mt * 16 + rA) * 264 + kb * 32 + k8r * 8];
#pragma unroll
        for (int dt = 0; dt < 2; ++dt) {
            short8v vb = *(const short8v*)&Vt[(dt * 16 + rA) * 264 + kb * 32 + k8r * 8];
            o[dt] = __builtin_amdgcn_mfma_f32_16x16x32_bf16(pa, vb, o[dt], 0, 0, 0);
        }
    }

    {
        int bn = bh >> 3, h = bh & 7;
#pragma unroll
        for (int dt = 0; dt < 2; ++dt) {
            int d = dt * 16 + rA;
#pragma unroll
            for (int r = 0; r < 4; ++r) {
                int qq = mt * 16 + g * 4 + r;
                int l = (qv0 + (qq >> 5)) * 32 + (qq & 31);
                ctx[((size_t)bn * 1024 + l) * 256 + h * 32 + d] = f2bf(o[dt][r] * inv[r]);
            }
        }
    }
}

// ---------------------------------------------------------------------------
// K4: out_proj + residual(bf16) + LN2.  32-row tile, 512 threads / 8 waves,
// BK=64, global_load_lds staging.
// ---------------------------------------------------------------------------
__global__ __launch_bounds__(512) void outproj_ln_kernel(
    const unsigned short* __restrict__ ctx, const unsigned short* __restrict__ Wop,
    unsigned short* __restrict__ epi_b, const float* __restrict__ g2,
    const float* __restrict__ b2, unsigned short* __restrict__ ffin)
{
    __shared__ unsigned short As[32 * 64];
    __shared__ unsigned short Ws[256 * 64];
    __shared__ float part[2][4][4][4][2];

    int tid = threadIdx.x, lane = tid & 63, wv = tid >> 6;
    int m0 = blockIdx.x * 32;
    int rA = lane & 15, k8r = lane >> 4, g = lane >> 4;
    int rg = wv & 1, ch = wv >> 1;

    f32x4 acc[4];
#pragma unroll
    for (int ct = 0; ct < 4; ++ct)
#pragma unroll
        for (int r = 0; r < 4; ++r) acc[ct][r] = 0.f;

    for (int kc = 0; kc < 256; kc += 64) {
        if (wv < 4) {
            int cb = wv * 64;
            int c = cb + lane;
            int row = c >> 3, k8p = (c & 7) ^ (row & 7);
            __builtin_amdgcn_global_load_lds(
                (const unsigned int*)(ctx + (size_t)(m0 + row) * 256 + kc + k8p * 8),
                (unsigned int*)&As[cb * 8], 16, 0, 0);
        }
#pragma unroll
        for (int t = 0; t < 4; ++t) {
            int cb = (t * 8 + wv) * 64;
            int c = cb + lane;
            int row = c >> 3, k8p = (c & 7) ^ (row & 7);
            __builtin_amdgcn_global_load_lds(
                (const unsigned int*)(Wop + (size_t)row * 256 + kc + k8p * 8),
                (unsigned int*)&Ws[cb * 8], 16, 0, 0);
        }
        __syncthreads();

        short8v a[2];
#pragma unroll
        for (int ks = 0; ks < 2; ++ks) {
            int row = rg * 16 + rA;
            int cx = (ks * 4 + k8r) ^ (row & 7);
            a[ks] = *(const short8v*)&As[row * 64 + cx * 8];
        }
#pragma unroll
        for (int ks = 0; ks < 2; ++ks)
#pragma unroll
            for (int ct = 0; ct < 4; ++ct) {
                int row = ch * 64 + ct * 16 + rA;
                int cx = (ks * 4 + k8r) ^ (row & 7);
                short8v b = *(const short8v*)&Ws[row * 64 + cx * 8];
                acc[ct] = __builtin_amdgcn_mfma_f32_16x16x32_bf16(a[ks], b, acc[ct], 0, 0, 0);
            }
        __syncthreads();
    }

    float s[4] = {0.f, 0.f, 0.f, 0.f}, q[4] = {0.f, 0.f, 0.f, 0.f};
#pragma unroll
    for (int ct = 0; ct < 4; ++ct) {
        int col = ch * 64 + ct * 16 + rA;
#pragma unroll
        for (int r = 0; r < 4; ++r) {
            int row = m0 + rg * 16 + g * 4 + r;
            float v = acc[ct][r] + bf2f(epi_b[(size_t)row * 256 + col]);
            acc[ct][r] = v;
            s[r] += v; q[r] += v * v;
        }
    }
#pragma unroll
    for (int off = 8; off; off >>= 1)
#pragma unroll
        for (int r = 0; r < 4; ++r) {
            s[r] += __shfl_xor(s[r], off);
            q[r] += __shfl_xor(q[r], off);
        }
    if (rA == 0) {
#pragma unroll
        for (int r = 0; r < 4; ++r) {
            part[rg][ch][g][r][0] = s[r];
            part[rg][ch][g][r][1] = q[r];
        }
    }
    __syncthreads();
    float mu[4], rs[4];
#pragma unroll
    for (int r = 0; r < 4; ++r) {
        float S = part[rg][0][g][r][0] + part[rg][1][g][r][0]
                + part[rg][2][g][r][0] + part[rg][3][g][r][0];
        float Q = part[rg][0][g][r][1] + part[rg][1][g][r][1]
                + part[rg][2][g][r][1] + part[rg][3][g][r][1];
        mu[r] = S * (1.f / 256.f);
        rs[r] = rsqrtf(Q * (1.f / 256.f) - mu[r] * mu[r] + 1e-5f);
    }
#pragma unroll
    for (int ct = 0; ct < 4; ++ct) {
        int col = ch * 64 + ct * 16 + rA;
        float gg = g2[col], bv = b2[col];
#pragma unroll
        for (int r = 0; r < 4; ++r) {
            int row = m0 + rg * 16 + g * 4 + r;
            size_t o = (size_t)row * 256 + col;
            epi_b[o] = f2bf(acc[ct][r]);
            ffin[o] = f2bf((acc[ct][r] - mu[r]) * rs[r] * gg + bv);
        }
    }
}

// ---------------------------------------------------------------------------
// K6: FF2 + residual(bf16) + final E->32 projection + transposed store.
// 32-row tile, 512 threads / 8 waves, BK=64, global_load_lds staging.
// ---------------------------------------------------------------------------
__global__ __launch_bounds__(512) void ff2_final_kernel(
    const unsigned short* __restrict__ ffh, const unsigned short* __restrict__ W2,
    const unsigned short* __restrict__ epi_b, const float* __restrict__ w_out,
    float* __restrict__ out)
{
    __shared__ unsigned short As[32 * 64];
    __shared__ unsigned short Ws[256 * 64];
    __shared__ unsigned short Ts[32 * 264];

    int tid = threadIdx.x, lane = tid & 63, wv = tid >> 6;
    int m0 = blockIdx.x * 32;
    int rA = lane & 15, k8r = lane >> 4, g = lane >> 4;
    int rg = wv & 1, ch = wv >> 1;

    f32x4 acc[4];
#pragma unroll
    for (int ct = 0; ct < 4; ++ct)
#pragma unroll
        for (int r = 0; r < 4; ++r) acc[ct][r] = 0.f;

    for (int kc = 0; kc < 512; kc += 64) {
        if (wv < 4) {
            int cb = wv * 64;
            int c = cb + lane;
            int row = c >> 3, k8p = (c & 7) ^ (row & 7);
            __builtin_amdgcn_global_load_lds(
                (const unsigned int*)(ffh + (size_t)(m0 + row) * 512 + kc + k8p * 8),
                (unsigned int*)&As[cb * 8], 16, 0, 0);
        }
#pragma unroll
        for (int t = 0; t < 4; ++t) {
            int cb = (t * 8 + wv) * 64;
            int c = cb + lane;
            int row = c >> 3, k8p = (c & 7) ^ (row & 7);
            __builtin_amdgcn_global_load_lds(
                (const unsigned int*)(W2 + (size_t)row * 512 + kc + k8p * 8),
                (unsigned int*)&Ws[cb * 8], 16, 0, 0);
        }
        __syncthreads();

        short8v a[2];
#pragma unroll
        for (int ks = 0; ks < 2; ++ks) {
            int row = rg * 16 + rA;
            int cx = (ks * 4 + k8r) ^ (row & 7);
            a[ks] = *(const short8v*)&As[row * 64 + cx * 8];
        }
#pragma unroll
        for (int ks = 0; ks < 2; ++ks)
#pragma unroll
            for (int ct = 0; ct < 4; ++ct) {
                int row = ch * 64 + ct * 16 + rA;
                int cx = (ks * 4 + k8r) ^ (row & 7);
                short8v b = *(const short8v*)&Ws[row * 64 + cx * 8];
                acc[ct] = __builtin_amdgcn_mfma_f32_16x16x32_bf16(a[ks], b, acc[ct], 0, 0, 0);
            }
        __syncthreads();
    }

#pragma unroll
    for (int ct = 0; ct < 4; ++ct) {
        int col = ch * 64 + ct * 16 + rA;
#pragma unroll
        for (int r = 0; r < 4; ++r) {
            int lrow = rg * 16 + g * 4 + r;
            float v = acc[ct][r] + bf2f(epi_b[(size_t)(m0 + lrow) * 256 + col]);
            Ts[lrow * 264 + col] = f2bf(v);
        }
    }
    __syncthreads();

    int bn = m0 >> 10, l0 = m0 & 1023;
    int bb = bn >> 2, nn = bn & 3;

    if (wv < 4) {
        int rw = wv & 1, cw = wv >> 1;
        f32x4 a2;
#pragma unroll
        for (int r = 0; r < 4; ++r) a2[r] = 0.f;
#pragma unroll
        for (int ks = 0; ks < 8; ++ks) {
            short8v af = *(const short8v*)&Ts[(rw * 16 + rA) * 264 + ks * 32 + k8r * 8];
            const float* wp = w_out + (cw * 16 + rA) * 256 + ks * 32 + k8r * 8;
            float4 w0 = *(const float4*)wp;
            float4 w1 = *(const float4*)(wp + 4);
            short8v bf;
            bf[0] = (short)f2bf(w0.x); bf[1] = (short)f2bf(w0.y);
            bf[2] = (short)f2bf(w0.z); bf[3] = (short)f2bf(w0.w);
            bf[4] = (short)f2bf(w1.x); bf[5] = (short)f2bf(w1.y);
            bf[6] = (short)f2bf(w1.z); bf[7] = (short)f2bf(w1.w);
            a2 = __builtin_amdgcn_mfma_f32_16x16x32_bf16(af, bf, a2, 0, 0, 0);
        }
        int c = cw * 16 + rA;
        int l = l0 + rw * 16 + g * 4;
        float4 st; st.x = a2[0]; st.y = a2[1]; st.z = a2[2]; st.w = a2[3];
        *(float4*)(out + ((size_t)(bb * 32 + c) * 4 + nn) * 1024 + l) = st;
    }
}

// ---------------------------------------------------------------------------
extern "C" void kernel_launch(void* const* d_in, const int* in_sizes, int n_in,
                              void* d_out, int out_size, void* d_ws, size_t ws_size,
                              hipStream_t stream) {
    const float* x_lf       = (const float*)d_in[0];
    const float* x_hf       = (const float*)d_in[1];
    const float* w_in       = (const float*)d_in[2];
    const float* w_qk       = (const float*)d_in[3];
    const float* ln_g       = (const float*)d_in[4];
    const float* ln_b       = (const float*)d_in[5];
    const float* in_proj_w  = (const float*)d_in[6];
    const float* out_proj_w = (const float*)d_in[7];
    const float* ln2_g      = (const float*)d_in[8];
    const float* ln2_b      = (const float*)d_in[9];
    const float* ff_w1      = (const float*)d_in[10];
    const float* ff_w2      = (const float*)d_in[11];
    const float* w_out      = (const float*)d_in[12];
    float* out = (float*)d_out;

    char* w = (char*)d_ws;
    unsigned short* epi_b  = (unsigned short*)(w);                // 4 MB bf16
    unsigned short* Qb     = (unsigned short*)(w + (4u  << 20));  // 4 MB bf16
    unsigned short* Kb     = (unsigned short*)(w + (8u  << 20));
    unsigned short* Vb     = (unsigned short*)(w + (12u << 20));
    unsigned short* q_b    = (unsigned short*)(w + (16u << 20));
    unsigned short* k_b    = (unsigned short*)(w + (20u << 20));
    unsigned short* kv_b   = (unsigned short*)(w + (24u << 20));
    unsigned short* ctx_b  = (unsigned short*)(w + (28u << 20));
    unsigned short* ffin_b = (unsigned short*)(w + (32u << 20));
    unsigned short* ffh_b  = (unsigned short*)(w + (36u << 20));  // 8 MB
    unsigned short* wqkv_b = (unsigned short*)(w + (44u << 20));
    unsigned short* wop_b  = (unsigned short*)(w + (45u << 20));
    unsigned short* wff1_b = (unsigned short*)(w + (46u << 20));
    unsigned short* wff2_b = (unsigned short*)(w + (47u << 20));

    // 1. gather + input proj + dual LN + weight conversion  [256 blk x 512]
    embed_conv_kernel<<<256, 512, 0, stream>>>(
        x_lf, x_hf, w_in, w_qk, ln_g, ln_b, epi_b, kv_b, q_b, k_b,
        in_proj_w, out_proj_w, ff_w1, ff_w2, wqkv_b, wop_b, wff1_b, wff2_b);
    // 2. QKV projection -> bf16 (bn,h,l,d)   [768 blocks, gload_lds]
    gemm_mfma64<1, false><<<dim3(128, 2, 3), 256, 0, stream>>>(
        q_b, k_b, kv_b, wqkv_b, Qb, 256, 256);
    // 3. local-window attention (MFMA, 2 qv-rows/block) -> ctx bf16
    attn_mfma_kernel<<<1024, 256, 0, stream>>>(Qb, Kb, Vb, ctx_b);
    // 4. out_proj + residual(bf16) + LN2  [512 thr, gload_lds]
    outproj_ln_kernel<<<256, 512, 0, stream>>>(ctx_b, wop_b, epi_b,
                                               ln2_g, ln2_b, ffin_b);
    // 5. FF1 + ReLU -> bf16 [8192,512]   [512 blocks, gload_lds]
    gemm_mfma64<0, true><<<dim3(128, 4, 1), 256, 0, stream>>>(
        ffin_b, ffin_b, ffin_b, wff1_b, ffh_b, 256, 512);
    // 6. FF2 + residual(bf16) + final projection + transposed store
    ff2_final_kernel<<<256, 512, 0, stream>>>(ffh_b, wff2_b, epi_b, w_out, out);
}